// Round 1
// baseline (643.354 us; speedup 1.0000x reference)
//
#include <hip/hip_runtime.h>
#include <cfloat>

#define N_TOK 262144
#define DIM   64
#define KCB   512
#define BM    128
#define BK    64
#define TAU_HALF 0.0625f   // margin in (q/2 - s) units == 0.125 in distance units

// ---------------------------------------------------------------------------
// qhalf[k] = 0.5 * ||vq_k||^2
// ---------------------------------------------------------------------------
__global__ __launch_bounds__(256) void qhalf_kernel(const float* __restrict__ vq,
                                                    float* __restrict__ qhalf) {
    int k = blockIdx.x * blockDim.x + threadIdx.x;
    if (k >= KCB) return;
    const float* row = vq + (size_t)k * DIM;
    float s = 0.f;
#pragma unroll
    for (int d = 0; d < DIM; d += 4) {
        float4 v = *(const float4*)(row + d);
        s = fmaf(v.x, v.x, s);
        s = fmaf(v.y, v.y, s);
        s = fmaf(v.z, v.z, s);
        s = fmaf(v.w, v.w, s);
    }
    qhalf[k] = 0.5f * s;
}

// ---------------------------------------------------------------------------
// Main pass: fp32 scores t_k = qhalf[k] - x.vq_k ; running (min1,min2,argmin)
// per token.  Flags tokens whose margin (min2-min1) < TAU_HALF for exact
// fp64 refinement.
// Block: 256 threads (16 tx x 16 ty).  Tile: 128 tokens x 64 codewords,
// per-thread 8x4 outer product over d.
// ---------------------------------------------------------------------------
__global__ __launch_bounds__(256) void argmin_kernel(
    const float* __restrict__ x, const float* __restrict__ vq,
    const float* __restrict__ qhalf, int* __restrict__ idx_out,
    int* __restrict__ flag_cnt, int* __restrict__ flag_list)
{
    __shared__ float xt[64][132];   // [d][token], pad to 132 (16B-aligned rows)
    __shared__ float vt[64][68];    // [d][codeword]

    const int tid = threadIdx.x;
    const int m0  = blockIdx.x * BM;

    // load x tile transposed: lanes write consecutive rows -> conflict-free
#pragma unroll
    for (int j = 0; j < 8; ++j) {
        int id  = tid + j * 256;        // 0..2047
        int row = id & 127;
        int c4  = id >> 7;              // 0..15
        float4 v = *(const float4*)(x + (size_t)(m0 + row) * DIM + c4 * 4);
        xt[c4 * 4 + 0][row] = v.x;
        xt[c4 * 4 + 1][row] = v.y;
        xt[c4 * 4 + 2][row] = v.z;
        xt[c4 * 4 + 3][row] = v.w;
    }

    const int tx = tid & 15, ty = tid >> 4;
    float min1[8], min2[8];
    int   bidx[8];
#pragma unroll
    for (int m = 0; m < 8; ++m) { min1[m] = FLT_MAX; min2[m] = FLT_MAX; bidx[m] = 0; }

    for (int kt = 0; kt < KCB / BK; ++kt) {
        __syncthreads();                 // protect vt before overwrite
#pragma unroll
        for (int j = 0; j < 4; ++j) {
            int id  = tid + j * 256;     // 0..1023
            int row = id & 63;
            int c4  = id >> 6;           // 0..15
            float4 v = *(const float4*)(vq + (size_t)(kt * BK + row) * DIM + c4 * 4);
            vt[c4 * 4 + 0][row] = v.x;
            vt[c4 * 4 + 1][row] = v.y;
            vt[c4 * 4 + 2][row] = v.z;
            vt[c4 * 4 + 3][row] = v.w;
        }
        __syncthreads();

        float acc[8][4];
#pragma unroll
        for (int m = 0; m < 8; ++m)
#pragma unroll
            for (int j = 0; j < 4; ++j) acc[m][j] = 0.f;

#pragma unroll 4
        for (int d = 0; d < 64; ++d) {
            float4 xa = *(const float4*)&xt[d][ty * 8];
            float4 xb = *(const float4*)&xt[d][ty * 8 + 4];
            float4 vv = *(const float4*)&vt[d][tx * 4];
            float xr[8] = {xa.x, xa.y, xa.z, xa.w, xb.x, xb.y, xb.z, xb.w};
            float vr[4] = {vv.x, vv.y, vv.z, vv.w};
#pragma unroll
            for (int m = 0; m < 8; ++m)
#pragma unroll
                for (int j = 0; j < 4; ++j)
                    acc[m][j] = fmaf(xr[m], vr[j], acc[m][j]);
        }

        int kbase = kt * BK + tx * 4;
        float qh[4] = {qhalf[kbase + 0], qhalf[kbase + 1],
                       qhalf[kbase + 2], qhalf[kbase + 3]};
#pragma unroll
        for (int m = 0; m < 8; ++m) {
#pragma unroll
            for (int j = 0; j < 4; ++j) {
                float t = qh[j] - acc[m][j];
                if (t < min1[m]) {
                    min2[m] = min1[m]; min1[m] = t; bidx[m] = kbase + j;
                } else if (t < min2[m]) {
                    min2[m] = t;
                }
            }
        }
    }

    // reduce across the 16 tx lanes (same 8 token rows)
#pragma unroll
    for (int m = 0; m < 8; ++m) {
        float a1 = min1[m], a2 = min2[m];
        int   ai = bidx[m];
#pragma unroll
        for (int s = 1; s < 16; s <<= 1) {
            float b1 = __shfl_xor(a1, s, 64);
            float b2 = __shfl_xor(a2, s, 64);
            int   bi = __shfl_xor(ai, s, 64);
            if (b1 < a1 || (b1 == a1 && bi < ai)) {
                a2 = fminf(a1, b2); a1 = b1; ai = bi;
            } else {
                a2 = fminf(a2, b1);
            }
        }
        if (tx == 0) {
            int token = m0 + ty * 8 + m;
            idx_out[token] = ai;
            if (a2 - a1 < TAU_HALF) {
                int p = atomicAdd(flag_cnt, 1);
                flag_list[p] = token;
            }
        }
    }
}

// ---------------------------------------------------------------------------
// Exact fp64 re-argmin for flagged tokens.  One wave handles 8 tokens;
// 8 lanes/token each own an 8-wide d-slice.
// ---------------------------------------------------------------------------
__global__ __launch_bounds__(256) void refine_kernel(
    const float* __restrict__ x, const float* __restrict__ vq,
    const int* __restrict__ flag_cnt, const int* __restrict__ flag_list,
    int* __restrict__ idx_out)
{
    int cnt = *flag_cnt;
    if (cnt <= 0) return;
    int lane = threadIdx.x & 63;
    int wid  = (blockIdx.x * blockDim.x + threadIdx.x) >> 6;
    int nw   = (gridDim.x * blockDim.x) >> 6;
    int tg   = lane >> 3;          // token slot 0..7
    int dl   = (lane & 7) * 8;     // d-slice start

    for (int base = wid * 8; base < cnt; base += nw * 8) {
        int fi = base + tg;
        if (fi >= cnt) fi = cnt - 1;          // duplicate work, same result
        int token = flag_list[fi];
        double xd[8];
#pragma unroll
        for (int j = 0; j < 8; ++j)
            xd[j] = (double)x[(size_t)token * DIM + dl + j];

        double best = DBL_MAX;
        int bk = 0;
        for (int k = 0; k < KCB; ++k) {
            const float* vr = vq + (size_t)k * DIM + dl;
            float4 v0 = *(const float4*)(vr);
            float4 v1 = *(const float4*)(vr + 4);
            float vf[8] = {v0.x, v0.y, v0.z, v0.w, v1.x, v1.y, v1.z, v1.w};
            double p = 0.0;
#pragma unroll
            for (int j = 0; j < 8; ++j) {
                double dd = xd[j] - (double)vf[j];
                p = fma(dd, dd, p);
            }
            // butterfly within the 8-lane group: all lanes get identical sum
            p += __shfl_xor(p, 1, 64);
            p += __shfl_xor(p, 2, 64);
            p += __shfl_xor(p, 4, 64);
            if (p < best) { best = p; bk = k; }   // strict < : first k on ties
        }
        if ((lane & 7) == 0) idx_out[token] = bk;
    }
}

// ---------------------------------------------------------------------------
// Gather quantized rows + LDS segment-sum into per-(block,p / k-chunk)
// partials.  grid = P*4 blocks; block (p, c) owns token range p and
// codeword chunk [c*128, c*128+128).
// ---------------------------------------------------------------------------
__global__ __launch_bounds__(256) void gather_segsum_kernel(
    const float* __restrict__ x, const float* __restrict__ vq,
    const int* __restrict__ idx, float* __restrict__ quant,
    float* __restrict__ part_cs, float* __restrict__ part_cn,
    int chunk_tok)
{
    __shared__ float acc[128 * 64];   // 32 KB
    __shared__ float accn[128];

    int b = blockIdx.x;
    int p = b >> 2;
    int c = b & 3;
    int klo = c * 128;
    int tid = threadIdx.x;

    for (int i = tid; i < 128 * 64; i += 256) acc[i] = 0.f;
    if (tid < 128) accn[tid] = 0.f;
    __syncthreads();

    int t0 = p * chunk_tok;
    int t1 = t0 + chunk_tok;
    if (t1 > N_TOK) t1 = N_TOK;
    int tl = tid >> 4;     // token slot 0..15
    int c4 = tid & 15;

    for (int t = t0 + tl; t < t1; t += 16) {
        int k = idx[t];
        if (c == 0) {
            float4 v = *(const float4*)(vq + (size_t)k * DIM + c4 * 4);
            *(float4*)(quant + (size_t)t * DIM + c4 * 4) = v;
        }
        int kl = k - klo;
        if ((unsigned)kl < 128u) {
            float4 xv = *(const float4*)(x + (size_t)t * DIM + c4 * 4);
            float* dst = acc + kl * 64 + c4 * 4;
            atomicAdd(dst + 0, xv.x);
            atomicAdd(dst + 1, xv.y);
            atomicAdd(dst + 2, xv.z);
            atomicAdd(dst + 3, xv.w);
            if (c4 == 0) atomicAdd(&accn[kl], 1.0f);
        }
    }
    __syncthreads();

    // flush partials (write-only, no zeroing of ws needed)
    for (int i = tid; i < 128 * 64 / 4; i += 256) {
        *(float4*)(part_cs + (size_t)p * (KCB * DIM) + c * 8192 + i * 4) =
            *(const float4*)(acc + i * 4);
    }
    if (tid < 128) part_cn[(size_t)p * KCB + klo + tid] = accn[tid];
}

// ---------------------------------------------------------------------------
// Deterministic tree reduce of partials + EMA + division.
// ---------------------------------------------------------------------------
__global__ __launch_bounds__(256) void finalize_kernel(
    const float* __restrict__ part_cs, const float* __restrict__ part_cn,
    const float* __restrict__ cs_old, const float* __restrict__ cn_old,
    float* __restrict__ out_vq, float* __restrict__ out_cs,
    float* __restrict__ out_cn, int P)
{
    int gid = blockIdx.x * blockDim.x + threadIdx.x;
    if (gid >= KCB * DIM) return;
    int k = gid >> 6;
    float scs = 0.f, scn = 0.f;
    for (int p = 0; p < P; ++p) {
        scs += part_cs[(size_t)p * (KCB * DIM) + gid];
        scn += part_cn[(size_t)p * KCB + k];
    }
    const float A = (float)0.99;          // matches f32(GAMMA)
    const float B = (float)(1.0 - 0.99);  // computed in f64 then cast, as in ref
    float ncs = cs_old[gid] * A + scs * B;
    float ncn = cn_old[k] * A + scn * B;
    out_cs[gid] = ncs;
    out_vq[gid] = ncs / ncn;
    if ((gid & 63) == 0) out_cn[k] = ncn;
}

// ---------------------------------------------------------------------------
extern "C" void kernel_launch(void* const* d_in, const int* in_sizes, int n_in,
                              void* d_out, int out_size, void* d_ws, size_t ws_size,
                              hipStream_t stream)
{
    const float* x      = (const float*)d_in[0];
    const float* vq     = (const float*)d_in[1];
    const float* cs_old = (const float*)d_in[2];
    const float* cn_old = (const float*)d_in[3];

    float* out_q  = (float*)d_out;
    float* out_vq = out_q + (size_t)N_TOK * DIM;
    float* out_cs = out_vq + (size_t)KCB * DIM;
    float* out_cn = out_cs + (size_t)KCB * DIM;

    char* ws = (char*)d_ws;
    int*   idx       = (int*)(ws);                          // 1 MB
    int*   flag_list = (int*)(ws + (1 << 20));              // 1 MB
    int*   flag_cnt  = (int*)(ws + (2 << 20));              // 4 B
    float* qhalf     = (float*)(ws + (2 << 20) + 256);      // 2 KB
    float* part_cn   = (float*)(ws + (2 << 20) + 4096);     // <= 512 KB
    float* part_cs   = (float*)(ws + (3 << 20));            // P * 128 KB

    size_t avail = ws_size > (size_t)(3 << 20) ? ws_size - (size_t)(3 << 20) : 0;
    int P = (int)(avail / ((size_t)KCB * DIM * 4));
    if (P > 256) P = 256;
    if (P < 1) P = 1;
    int chunk_tok = (N_TOK + P - 1) / P;

    hipMemsetAsync(flag_cnt, 0, 4, stream);
    qhalf_kernel<<<2, 256, 0, stream>>>(vq, qhalf);
    argmin_kernel<<<N_TOK / BM, 256, 0, stream>>>(x, vq, qhalf, idx, flag_cnt, flag_list);
    refine_kernel<<<128, 256, 0, stream>>>(x, vq, flag_cnt, flag_list, idx);
    gather_segsum_kernel<<<P * 4, 256, 0, stream>>>(x, vq, idx, out_q,
                                                    part_cs, part_cn, chunk_tok);
    finalize_kernel<<<128, 256, 0, stream>>>(part_cs, part_cn, cs_old, cn_old,
                                             out_vq, out_cs, out_cn, P);
}

// Round 2
// 310.021 us; speedup vs baseline: 2.0752x; 2.0752x over previous
//
#include <hip/hip_runtime.h>
#include <cfloat>

typedef _Float16 f16x8 __attribute__((ext_vector_type(8)));
typedef _Float16 f16x4 __attribute__((ext_vector_type(4)));
typedef float    f32x4 __attribute__((ext_vector_type(4)));

#define N_TOK 262144
#define DIM   64
#define KCB   512
#define BMT   128          // tokens per argmin block
#define TAU_T 0.0625f      // flag threshold in half-distance units (dist 0.125)

// ---------------------------------------------------------------------------
// prep: qhalf[k] = 0.5*||v_k||^2 (f32), qd[k] = ||v_k||^2 (f64, for refine)
// ---------------------------------------------------------------------------
__global__ __launch_bounds__(256) void prep_kernel(const float* __restrict__ vq,
        float* __restrict__ qhalf, double* __restrict__ qd) {
    int k = blockIdx.x * 256 + threadIdx.x;
    if (k >= KCB) return;
    const float* row = vq + (size_t)k * DIM;
    double s = 0.0;
#pragma unroll
    for (int d = 0; d < DIM; d += 4) {
        float4 g = *(const float4*)(row + d);
        s = fma((double)g.x, (double)g.x, s);
        s = fma((double)g.y, (double)g.y, s);
        s = fma((double)g.z, (double)g.z, s);
        s = fma((double)g.w, (double)g.w, s);
    }
    qd[k] = s;
    qhalf[k] = (float)(0.5 * s);
}

// ---------------------------------------------------------------------------
// MFMA argmin: acc = -q/2 + x_hi.v + x_lo.v  (argmax acc == argmin dist).
// Block: 256 thr = 4 waves, 128 tokens; codes looped in 8 chunks of 64.
// Per wave: 32 tokens (2 subtiles of 16), 4 code subtiles -> 8 acc tiles,
// 32 MFMA (16x16x32 f16) per chunk.  Writes idx, flags, quantized.
// ---------------------------------------------------------------------------
__global__ __launch_bounds__(256) void argmin_mfma_kernel(
    const float* __restrict__ x, const float* __restrict__ vq,
    const float* __restrict__ qhalf, int* __restrict__ idx_out,
    int* __restrict__ flag_cnt, int* __restrict__ flag_list,
    float* __restrict__ quant)
{
    __shared__ _Float16 xh[BMT * DIM];      // 16 KB, swizzled
    __shared__ _Float16 xl[BMT * DIM];      // 16 KB
    __shared__ _Float16 vh[2][64 * DIM];    // 16 KB dbuf
    __shared__ float    qhn[KCB];           // 2 KB, holds -q/2
    __shared__ int      idx_lds[BMT];

    const int tid = threadIdx.x;
    const int m0  = blockIdx.x * BMT;

    // stage x -> split f16 hi/lo (coalesced: 16 lanes span one row)
#pragma unroll
    for (int j = 0; j < 8; ++j) {
        int id = tid + j * 256;
        int row = id >> 4, c4 = id & 15;
        float4 g = *(const float4*)(x + (size_t)(m0 + row) * DIM + c4 * 4);
        f16x4 hi, lo;
        hi[0] = (_Float16)g.x; lo[0] = (_Float16)(g.x - (float)hi[0]);
        hi[1] = (_Float16)g.y; lo[1] = (_Float16)(g.y - (float)hi[1]);
        hi[2] = (_Float16)g.z; lo[2] = (_Float16)(g.z - (float)hi[2]);
        hi[3] = (_Float16)g.w; lo[3] = (_Float16)(g.w - (float)hi[3]);
        int h = (row * DIM + c4 * 4) ^ ((row & 7) << 3);
        *(f16x4*)(xh + h) = hi;
        *(f16x4*)(xl + h) = lo;
    }
    qhn[tid]       = -qhalf[tid];
    qhn[tid + 256] = -qhalf[tid + 256];
    // stage vq chunk 0
#pragma unroll
    for (int j = 0; j < 4; ++j) {
        int id = tid + j * 256;
        int row = id >> 4, c4 = id & 15;
        float4 g = *(const float4*)(vq + (size_t)row * DIM + c4 * 4);
        f16x4 hi = {(_Float16)g.x, (_Float16)g.y, (_Float16)g.z, (_Float16)g.w};
        int h = (row * DIM + c4 * 4) ^ ((row & 7) << 3);
        *(f16x4*)(vh[0] + h) = hi;
    }
    __syncthreads();

    const int lane = tid & 63, w = tid >> 6;
    const int grp = lane >> 4, li = lane & 15;

    float m1[2] = {-FLT_MAX, -FLT_MAX};
    float m2[2] = {-FLT_MAX, -FLT_MAX};
    int   i1[2] = {0, 0};

    for (int ch = 0; ch < 8; ++ch) {
        const int cur = ch & 1;
        float4 gv[4];
        if (ch < 7) {                       // T14: issue next-chunk loads early
#pragma unroll
            for (int j = 0; j < 4; ++j) {
                int id = tid + j * 256;
                int row = id >> 4, c4 = id & 15;
                gv[j] = *(const float4*)(vq + (size_t)((ch + 1) * 64 + row) * DIM + c4 * 4);
            }
        }
        // acc init = -q/2 (broadcast reads)
        f32x4 acc[4][2];
#pragma unroll
        for (int tc = 0; tc < 4; ++tc) {
            float4 q = *(const float4*)&qhn[ch * 64 + tc * 16 + grp * 4];
            f32x4 qi = {q.x, q.y, q.z, q.w};
            acc[tc][0] = qi; acc[tc][1] = qi;
        }
#pragma unroll
        for (int kk = 0; kk < 2; ++kk) {
            f16x8 a[4], bh[2], bl[2];
#pragma unroll
            for (int tc = 0; tc < 4; ++tc) {
                int r = tc * 16 + li;
                int h = (r * DIM + kk * 32 + grp * 8) ^ ((r & 7) << 3);
                a[tc] = *(const f16x8*)(vh[cur] + h);
            }
#pragma unroll
            for (int tt = 0; tt < 2; ++tt) {
                int r = w * 32 + tt * 16 + li;
                int h = (r * DIM + kk * 32 + grp * 8) ^ ((r & 7) << 3);
                bh[tt] = *(const f16x8*)(xh + h);
                bl[tt] = *(const f16x8*)(xl + h);
            }
#pragma unroll
            for (int tc = 0; tc < 4; ++tc)
#pragma unroll
                for (int tt = 0; tt < 2; ++tt) {
                    acc[tc][tt] = __builtin_amdgcn_mfma_f32_16x16x32_f16(a[tc], bh[tt], acc[tc][tt], 0, 0, 0);
                    acc[tc][tt] = __builtin_amdgcn_mfma_f32_16x16x32_f16(a[tc], bl[tt], acc[tc][tt], 0, 0, 0);
                }
        }
        // epilogue: branchless (max1,max2,argmax) per token column
#pragma unroll
        for (int tc = 0; tc < 4; ++tc)
#pragma unroll
            for (int tt = 0; tt < 2; ++tt)
#pragma unroll
                for (int j = 0; j < 4; ++j) {
                    float t = acc[tc][tt][j];
                    int id = ch * 64 + tc * 16 + grp * 4 + j;
                    float old1 = m1[tt];
                    bool c = t > old1;
                    m2[tt] = fmaxf(m2[tt], c ? old1 : t);
                    m1[tt] = c ? t : old1;
                    i1[tt] = c ? id : i1[tt];
                }
        // write next chunk into other buffer
        if (ch < 7) {
#pragma unroll
            for (int j = 0; j < 4; ++j) {
                int id = tid + j * 256;
                int row = id >> 4, c4 = id & 15;
                f16x4 hi = {(_Float16)gv[j].x, (_Float16)gv[j].y,
                            (_Float16)gv[j].z, (_Float16)gv[j].w};
                int h = (row * DIM + c4 * 4) ^ ((row & 7) << 3);
                *(f16x4*)(vh[cur ^ 1] + h) = hi;
            }
        }
        __syncthreads();
    }

    // merge the 4 row-lane-groups per token; ties -> smaller code index
#pragma unroll
    for (int tt = 0; tt < 2; ++tt) {
        float v1 = m1[tt], v2 = m2[tt];
        int ix = i1[tt];
#pragma unroll
        for (int s = 16; s <= 32; s <<= 1) {
            float o1 = __shfl_xor(v1, s, 64);
            float o2 = __shfl_xor(v2, s, 64);
            int   oi = __shfl_xor(ix, s, 64);
            v2 = fmaxf(v2, fmaxf(o2, fminf(v1, o1)));
            bool c = (o1 > v1) || (o1 == v1 && oi < ix);
            v1 = c ? o1 : v1;
            ix = c ? oi : ix;
        }
        if (lane < 16) {
            int ltok = w * 32 + tt * 16 + li;
            idx_lds[ltok] = ix;
            idx_out[m0 + ltok] = ix;
            if (v1 - v2 < TAU_T) {
                int p = atomicAdd(flag_cnt, 1);
                flag_list[p] = m0 + ltok;
            }
        }
    }
    __syncthreads();

    // quantized gather (refine later overwrites flagged rows)
#pragma unroll
    for (int j = 0; j < 8; ++j) {
        int id = tid + j * 256;
        int row = id >> 4, c4 = id & 15;
        int k = idx_lds[row];
        float4 v = *(const float4*)(vq + (size_t)k * DIM + c4 * 4);
        *(float4*)(quant + (size_t)(m0 + row) * DIM + c4 * 4) = v;
    }
}

// ---------------------------------------------------------------------------
// Exact fp64 re-argmin of flagged tokens. vq staged fp32 in LDS (stride 68
// floats -> conflict-free b128). 1 wave/token, 8 codes/lane (c = lane+64*jj).
// dist = qd[c] - 2*x.v in fp64; ties -> smallest c. Rewrites idx + quant row.
// ---------------------------------------------------------------------------
__global__ __launch_bounds__(256) void refine_kernel(
    const float* __restrict__ x, const float* __restrict__ vq,
    const double* __restrict__ qd,
    const int* __restrict__ flag_cnt, const int* __restrict__ flag_list,
    int* __restrict__ idx_out, float* __restrict__ quant)
{
    __shared__ float vql[KCB * 68];   // 136 KB
    const int cnt = *flag_cnt;
    if (cnt <= 0) return;
    const int tid = threadIdx.x;
#pragma unroll
    for (int j = 0; j < 32; ++j) {
        int id = tid + j * 256;
        int c = id >> 4, dq = id & 15;
        float4 g = *(const float4*)(vq + (size_t)c * DIM + dq * 4);
        *(float4*)&vql[(c * 17 + dq) * 4] = g;
    }
    __syncthreads();
    const int lane = tid & 63, w = tid >> 6;

    for (int fi = blockIdx.x * 4 + w; fi < cnt; fi += 1024) {
        int token = flag_list[fi];
        const float* xr = x + (size_t)token * DIM;
        double xd[DIM];
#pragma unroll
        for (int dq = 0; dq < 16; ++dq) {
            float4 g = *(const float4*)(xr + dq * 4);
            xd[dq * 4 + 0] = (double)g.x;
            xd[dq * 4 + 1] = (double)g.y;
            xd[dq * 4 + 2] = (double)g.z;
            xd[dq * 4 + 3] = (double)g.w;
        }
        double best = DBL_MAX; int bc = 0;
#pragma unroll 1
        for (int jj = 0; jj < 8; ++jj) {
            int c = lane + jj * 64;
            double s = 0.0;
#pragma unroll
            for (int dq = 0; dq < 16; ++dq) {
                float4 v = *(const float4*)&vql[(c * 17 + dq) * 4];
                s = fma(xd[dq * 4 + 0], (double)v.x, s);
                s = fma(xd[dq * 4 + 1], (double)v.y, s);
                s = fma(xd[dq * 4 + 2], (double)v.z, s);
                s = fma(xd[dq * 4 + 3], (double)v.w, s);
            }
            double dist = qd[c] - 2.0 * s;
            if (dist < best) { best = dist; bc = c; }
        }
#pragma unroll
        for (int sh = 1; sh < 64; sh <<= 1) {
            double ob = __shfl_xor(best, sh, 64);
            int    oc = __shfl_xor(bc, sh, 64);
            bool c = (ob < best) || (ob == best && oc < bc);
            best = c ? ob : best;
            bc   = c ? oc : bc;
        }
        if (lane == 0) idx_out[token] = bc;
        if (lane < 16) {
            float4 v = *(const float4*)&vql[(bc * 17 + lane) * 4];
            *(float4*)(quant + (size_t)token * DIM + lane * 4) = v;
        }
    }
}

// ---------------------------------------------------------------------------
// Segment-sum: single pass, all 512 codes in 130 KB LDS, 1024-thread blocks.
// ---------------------------------------------------------------------------
__global__ __launch_bounds__(1024) void segsum_kernel(
    const float* __restrict__ x, const int* __restrict__ idx,
    float* __restrict__ part_cs, float* __restrict__ part_cn, int chunk_tok)
{
    __shared__ float acc[KCB * DIM];   // 128 KB
    __shared__ float accn[KCB];
    const int tid = threadIdx.x;
    const int p = blockIdx.x;
    float4 z = {0.f, 0.f, 0.f, 0.f};
#pragma unroll
    for (int j = 0; j < 8; ++j) *(float4*)&acc[(tid + j * 1024) * 4] = z;
    if (tid < KCB) accn[tid] = 0.f;
    __syncthreads();

    int t0 = p * chunk_tok;
    int t1 = t0 + chunk_tok; if (t1 > N_TOK) t1 = N_TOK;
    int tl = tid >> 4, c4 = tid & 15;
    for (int t = t0 + tl; t < t1; t += 64) {
        int k = idx[t];
        float4 xv = *(const float4*)(x + (size_t)t * DIM + c4 * 4);
        float* dst = acc + k * DIM + c4 * 4;
        atomicAdd(dst + 0, xv.x);
        atomicAdd(dst + 1, xv.y);
        atomicAdd(dst + 2, xv.z);
        atomicAdd(dst + 3, xv.w);
        if (c4 == 0) atomicAdd(&accn[k], 1.f);
    }
    __syncthreads();
#pragma unroll
    for (int j = 0; j < 8; ++j) {
        int i = tid + j * 1024;
        *(float4*)(part_cs + (size_t)p * (KCB * DIM) + i * 4) = *(const float4*)&acc[i * 4];
    }
    if (tid < KCB) part_cn[(size_t)p * KCB + tid] = accn[tid];
}

// ---------------------------------------------------------------------------
// Deterministic reduce + EMA + division.
// ---------------------------------------------------------------------------
__global__ __launch_bounds__(256) void finalize_kernel(
    const float* __restrict__ part_cs, const float* __restrict__ part_cn,
    const float* __restrict__ cs_old, const float* __restrict__ cn_old,
    float* __restrict__ out_vq, float* __restrict__ out_cs,
    float* __restrict__ out_cn, int P)
{
    int gid = blockIdx.x * blockDim.x + threadIdx.x;
    if (gid >= KCB * DIM) return;
    int k = gid >> 6;
    float scs = 0.f, scn = 0.f;
    for (int p = 0; p < P; ++p) {
        scs += part_cs[(size_t)p * (KCB * DIM) + gid];
        scn += part_cn[(size_t)p * KCB + k];
    }
    const float A = 0.99f;
    const float B = (float)(1.0 - 0.99);
    float ncs = cs_old[gid] * A + scs * B;
    float ncn = cn_old[k] * A + scn * B;
    out_cs[gid] = ncs;
    out_vq[gid] = ncs / ncn;
    if ((gid & 63) == 0) out_cn[k] = ncn;
}

// ---------------------------------------------------------------------------
extern "C" void kernel_launch(void* const* d_in, const int* in_sizes, int n_in,
                              void* d_out, int out_size, void* d_ws, size_t ws_size,
                              hipStream_t stream)
{
    const float* x      = (const float*)d_in[0];
    const float* vq     = (const float*)d_in[1];
    const float* cs_old = (const float*)d_in[2];
    const float* cn_old = (const float*)d_in[3];

    float* out_q  = (float*)d_out;
    float* out_vq = out_q + (size_t)N_TOK * DIM;
    float* out_cs = out_vq + (size_t)KCB * DIM;
    float* out_cn = out_cs + (size_t)KCB * DIM;

    char* ws = (char*)d_ws;
    int*    idx       = (int*)(ws);                           // 1 MB
    int*    flag_list = (int*)(ws + (1 << 20));               // 1 MB
    int*    flag_cnt  = (int*)(ws + (2 << 20));               // 4 B
    float*  qhalf     = (float*)(ws + (2 << 20) + 1024);      // 2 KB
    double* qd        = (double*)(ws + (2 << 20) + 8192);     // 4 KB
    float*  part_cn   = (float*)(ws + (2 << 20) + 16384);     // <= 512 KB
    float*  part_cs   = (float*)(ws + (3 << 20));             // P * 128 KB

    size_t avail = ws_size > (size_t)(3 << 20) ? ws_size - (size_t)(3 << 20) : 0;
    int P = (int)(avail / ((size_t)KCB * DIM * 4));
    if (P > 256) P = 256;
    if (P < 1) P = 1;
    int chunk_tok = (N_TOK + P - 1) / P;

    hipMemsetAsync(flag_cnt, 0, 4, stream);
    prep_kernel<<<2, 256, 0, stream>>>(vq, qhalf, qd);
    argmin_mfma_kernel<<<N_TOK / BMT, 256, 0, stream>>>(x, vq, qhalf, idx,
                                                        flag_cnt, flag_list, out_q);
    refine_kernel<<<256, 256, 0, stream>>>(x, vq, qd, flag_cnt, flag_list, idx, out_q);
    segsum_kernel<<<P, 1024, 0, stream>>>(x, idx, part_cs, part_cn, chunk_tok);
    finalize_kernel<<<128, 256, 0, stream>>>(part_cs, part_cn, cs_old, cn_old,
                                             out_vq, out_cs, out_cn, P);
}

// Round 4
// 175.217 us; speedup vs baseline: 3.6718x; 1.7694x over previous
//
#include <hip/hip_runtime.h>
#include <cfloat>

typedef _Float16 f16x8 __attribute__((ext_vector_type(8)));
typedef _Float16 f16x4 __attribute__((ext_vector_type(4)));
typedef float    f32x4 __attribute__((ext_vector_type(4)));

#define N_TOK 262144
#define DIM   64
#define KCB   512
#define BMT   128          // tokens per argmin block
#define TAU_T 0.0625f      // flag threshold in half-distance units (dist 0.125)
#define FIXS  262144.0f    // 2^18 fixed-point scale (exact pow2 f32 multiply)

// ---------------------------------------------------------------------------
// prep: qhalf[k] = 0.5*||v_k||^2 (f32), qd[k] = ||v_k||^2 (f64, for refine)
// ---------------------------------------------------------------------------
__global__ __launch_bounds__(256) void prep_kernel(const float* __restrict__ vq,
        float* __restrict__ qhalf, double* __restrict__ qd) {
    int k = blockIdx.x * 256 + threadIdx.x;
    if (k >= KCB) return;
    const float* row = vq + (size_t)k * DIM;
    double s = 0.0;
#pragma unroll
    for (int d = 0; d < DIM; d += 4) {
        float4 g = *(const float4*)(row + d);
        s = fma((double)g.x, (double)g.x, s);
        s = fma((double)g.y, (double)g.y, s);
        s = fma((double)g.z, (double)g.z, s);
        s = fma((double)g.w, (double)g.w, s);
    }
    qd[k] = s;
    qhalf[k] = (float)(0.5 * s);
}

// ---------------------------------------------------------------------------
// MFMA argmin (validated in R3): acc = -q/2 + x_hi.v + x_lo.v.
// 512 threads = 8 waves, 128 tokens/block.  Also: per-block histogram of
// chosen codes -> global counts[] (one atomic per (block,code)).
// ---------------------------------------------------------------------------
__global__ __launch_bounds__(512, 4) void argmin_mfma_kernel(
    const float* __restrict__ x, const float* __restrict__ vq,
    const float* __restrict__ qhalf, int* __restrict__ idx_out,
    int* __restrict__ flag_cnt, int* __restrict__ flag_list,
    float* __restrict__ quant, int* __restrict__ counts)
{
    __shared__ _Float16 xh[BMT * DIM];      // 16 KB, swizzled
    __shared__ _Float16 xl[BMT * DIM];      // 16 KB
    __shared__ _Float16 vh[2][64 * DIM];    // 16 KB dbuf
    __shared__ float    qhn[KCB];           // 2 KB, holds -q/2
    __shared__ int      idx_lds[BMT];
    __shared__ int      hist[KCB];          // 2 KB

    const int tid = threadIdx.x;
    const int m0  = blockIdx.x * BMT;

    hist[tid] = 0;   // tid < 512 == KCB

    // stage x -> split f16 hi/lo (16 lanes span one row: coalesced)
#pragma unroll
    for (int j = 0; j < 4; ++j) {
        int id = tid + j * 512;
        int row = id >> 4, c4 = id & 15;
        float4 g = *(const float4*)(x + (size_t)(m0 + row) * DIM + c4 * 4);
        f16x4 hi, lo;
        hi[0] = (_Float16)g.x; lo[0] = (_Float16)(g.x - (float)hi[0]);
        hi[1] = (_Float16)g.y; lo[1] = (_Float16)(g.y - (float)hi[1]);
        hi[2] = (_Float16)g.z; lo[2] = (_Float16)(g.z - (float)hi[2]);
        hi[3] = (_Float16)g.w; lo[3] = (_Float16)(g.w - (float)hi[3]);
        int h = (row * DIM + c4 * 4) ^ ((row & 7) << 3);
        *(f16x4*)(xh + h) = hi;
        *(f16x4*)(xl + h) = lo;
    }
    qhn[tid] = -qhalf[tid];
    // stage vq chunk 0
#pragma unroll
    for (int j = 0; j < 2; ++j) {
        int id = tid + j * 512;
        int row = id >> 4, c4 = id & 15;
        float4 g = *(const float4*)(vq + (size_t)row * DIM + c4 * 4);
        f16x4 hi = {(_Float16)g.x, (_Float16)g.y, (_Float16)g.z, (_Float16)g.w};
        int h = (row * DIM + c4 * 4) ^ ((row & 7) << 3);
        *(f16x4*)(vh[0] + h) = hi;
    }
    __syncthreads();

    const int lane = tid & 63, w = tid >> 6;
    const int grp = lane >> 4, li = lane & 15;

    float m1 = -FLT_MAX, m2 = -FLT_MAX;
    int   i1 = 0;

    for (int ch = 0; ch < 8; ++ch) {
        const int cur = ch & 1;
        float4 gv[2];
        if (ch < 7) {                       // T14: issue next-chunk loads early
#pragma unroll
            for (int j = 0; j < 2; ++j) {
                int id = tid + j * 512;
                int row = id >> 4, c4 = id & 15;
                gv[j] = *(const float4*)(vq + (size_t)((ch + 1) * 64 + row) * DIM + c4 * 4);
            }
        }
        f32x4 acc[4];
#pragma unroll
        for (int tc = 0; tc < 4; ++tc) {
            float4 q = *(const float4*)&qhn[ch * 64 + tc * 16 + grp * 4];
            f32x4 qi = {q.x, q.y, q.z, q.w};
            acc[tc] = qi;
        }
#pragma unroll
        for (int kk = 0; kk < 2; ++kk) {
            f16x8 a[4], bhf, blf;
#pragma unroll
            for (int tc = 0; tc < 4; ++tc) {
                int r = tc * 16 + li;
                int h = (r * DIM + kk * 32 + grp * 8) ^ ((r & 7) << 3);
                a[tc] = *(const f16x8*)(vh[cur] + h);
            }
            {
                int r = w * 16 + li;
                int h = (r * DIM + kk * 32 + grp * 8) ^ ((r & 7) << 3);
                bhf = *(const f16x8*)(xh + h);
                blf = *(const f16x8*)(xl + h);
            }
#pragma unroll
            for (int tc = 0; tc < 4; ++tc) {
                acc[tc] = __builtin_amdgcn_mfma_f32_16x16x32_f16(a[tc], bhf, acc[tc], 0, 0, 0);
                acc[tc] = __builtin_amdgcn_mfma_f32_16x16x32_f16(a[tc], blf, acc[tc], 0, 0, 0);
            }
        }
#pragma unroll
        for (int tc = 0; tc < 4; ++tc)
#pragma unroll
            for (int j = 0; j < 4; ++j) {
                float t = acc[tc][j];
                int id = ch * 64 + tc * 16 + grp * 4 + j;
                float old1 = m1;
                bool c = t > old1;
                m2 = fmaxf(m2, c ? old1 : t);
                m1 = c ? t : old1;
                i1 = c ? id : i1;
            }
        if (ch < 7) {
#pragma unroll
            for (int j = 0; j < 2; ++j) {
                int id = tid + j * 512;
                int row = id >> 4, c4 = id & 15;
                f16x4 hi = {(_Float16)gv[j].x, (_Float16)gv[j].y,
                            (_Float16)gv[j].z, (_Float16)gv[j].w};
                int h = (row * DIM + c4 * 4) ^ ((row & 7) << 3);
                *(f16x4*)(vh[cur ^ 1] + h) = hi;
            }
        }
        __syncthreads();
    }

    // merge the 4 row-lane-groups per token; ties -> smaller code index
    {
        float v1 = m1, v2 = m2;
        int ix = i1;
#pragma unroll
        for (int s = 16; s <= 32; s <<= 1) {
            float o1 = __shfl_xor(v1, s, 64);
            float o2 = __shfl_xor(v2, s, 64);
            int   oi = __shfl_xor(ix, s, 64);
            v2 = fmaxf(v2, fmaxf(o2, fminf(v1, o1)));
            bool c = (o1 > v1) || (o1 == v1 && oi < ix);
            v1 = c ? o1 : v1;
            ix = c ? oi : ix;
        }
        if (lane < 16) {
            int ltok = w * 16 + li;
            idx_lds[ltok] = ix;
            idx_out[m0 + ltok] = ix;
            if (v1 - v2 < TAU_T) {
                int p = atomicAdd(flag_cnt, 1);
                flag_list[p] = m0 + ltok;
            }
        }
    }
    __syncthreads();

    if (tid < BMT) atomicAdd(&hist[idx_lds[tid]], 1);

    // quantized gather (refine later overwrites flagged rows)
#pragma unroll
    for (int j = 0; j < 4; ++j) {
        int id = tid + j * 512;
        int row = id >> 4, c4 = id & 15;
        int k = idx_lds[row];
        float4 v = *(const float4*)(vq + (size_t)k * DIM + c4 * 4);
        *(float4*)(quant + (size_t)(m0 + row) * DIM + c4 * 4) = v;
    }
    __syncthreads();
    if (hist[tid] > 0) atomicAdd(&counts[tid], hist[tid]);
}

// ---------------------------------------------------------------------------
// Exact fp64 re-argmin of flagged tokens (validated).  Also patches counts[]
// when it flips an index.
// ---------------------------------------------------------------------------
__global__ __launch_bounds__(256) void refine_kernel(
    const float* __restrict__ x, const float* __restrict__ vq,
    const double* __restrict__ qd,
    const int* __restrict__ flag_cnt, const int* __restrict__ flag_list,
    int* __restrict__ idx_out, float* __restrict__ quant,
    int* __restrict__ counts)
{
    __shared__ float vql[KCB * 68];   // 136 KB
    const int cnt = *flag_cnt;
    if (cnt <= 0) return;
    const int tid = threadIdx.x;
#pragma unroll
    for (int j = 0; j < 32; ++j) {
        int id = tid + j * 256;
        int c = id >> 4, dq = id & 15;
        float4 g = *(const float4*)(vq + (size_t)c * DIM + dq * 4);
        *(float4*)&vql[(c * 17 + dq) * 4] = g;
    }
    __syncthreads();
    const int lane = tid & 63, w = tid >> 6;

    for (int fi = blockIdx.x * 4 + w; fi < cnt; fi += 1024) {
        int token = flag_list[fi];
        const float* xr = x + (size_t)token * DIM;
        double xd[DIM];
#pragma unroll
        for (int dq = 0; dq < 16; ++dq) {
            float4 g = *(const float4*)(xr + dq * 4);
            xd[dq * 4 + 0] = (double)g.x;
            xd[dq * 4 + 1] = (double)g.y;
            xd[dq * 4 + 2] = (double)g.z;
            xd[dq * 4 + 3] = (double)g.w;
        }
        double best = DBL_MAX; int bc = 0;
#pragma unroll 1
        for (int jj = 0; jj < 8; ++jj) {
            int c = lane + jj * 64;
            double s = 0.0;
#pragma unroll
            for (int dq = 0; dq < 16; ++dq) {
                float4 v = *(const float4*)&vql[(c * 17 + dq) * 4];
                s = fma(xd[dq * 4 + 0], (double)v.x, s);
                s = fma(xd[dq * 4 + 1], (double)v.y, s);
                s = fma(xd[dq * 4 + 2], (double)v.z, s);
                s = fma(xd[dq * 4 + 3], (double)v.w, s);
            }
            double dist = qd[c] - 2.0 * s;
            if (dist < best) { best = dist; bc = c; }
        }
#pragma unroll
        for (int sh = 1; sh < 64; sh <<= 1) {
            double ob = __shfl_xor(best, sh, 64);
            int    oc = __shfl_xor(bc, sh, 64);
            bool c = (ob < best) || (ob == best && oc < bc);
            best = c ? ob : best;
            bc   = c ? oc : bc;
        }
        if (lane == 0) {
            int old = idx_out[token];
            if (old != bc) {
                idx_out[token] = bc;
                atomicAdd(&counts[old], -1);
                atomicAdd(&counts[bc], 1);
            }
        }
        if (lane < 16) {
            float4 v = *(const float4*)&vql[(bc * 17 + lane) * 4];
            *(float4*)(quant + (size_t)token * DIM + lane * 4) = v;
        }
    }
}

// ---------------------------------------------------------------------------
// Exclusive scan of counts -> cursor; also EMA for centroid_n output.
// Single block, 512 threads.
// ---------------------------------------------------------------------------
__global__ __launch_bounds__(512) void scan_ema_kernel(
    const int* __restrict__ counts, int* __restrict__ cursor,
    const float* __restrict__ cn_old, float* __restrict__ out_cn)
{
    __shared__ int s[KCB];
    const int tid = threadIdx.x;
    int my = counts[tid];
    s[tid] = my;
    __syncthreads();
    for (int off = 1; off < KCB; off <<= 1) {
        int v = s[tid];
        int a = (tid >= off) ? s[tid - off] : 0;
        __syncthreads();
        s[tid] = v + a;
        __syncthreads();
    }
    cursor[tid] = s[tid] - my;      // exclusive
    out_cn[tid] = cn_old[tid] * 0.99f + (float)my * 0.01f;
}

// ---------------------------------------------------------------------------
// Counting-sort scatter: block scans 1024 tokens, local LDS hist, reserves
// per-code spans with ONE global atomic per (block,code), writes packed
// (k<<18 | t) entries.
// ---------------------------------------------------------------------------
__global__ __launch_bounds__(512) void scatter_kernel(
    const int* __restrict__ idx, int* __restrict__ cursor,
    int* __restrict__ sorted)
{
    __shared__ int lhist[KCB];
    __shared__ int lbase[KCB];
    const int tid = threadIdx.x;
    const int t0 = blockIdx.x * 1024;

    lhist[tid] = 0;
    __syncthreads();
    int k0 = idx[t0 + tid];
    int k1 = idx[t0 + 512 + tid];
    atomicAdd(&lhist[k0], 1);
    atomicAdd(&lhist[k1], 1);
    __syncthreads();
    int h = lhist[tid];
    lbase[tid] = (h > 0) ? atomicAdd(&cursor[tid], h) : 0;
    __syncthreads();
    lhist[tid] = 0;
    __syncthreads();
    int s0 = atomicAdd(&lhist[k0], 1);
    sorted[lbase[k0] + s0] = (k0 << 18) | (t0 + tid);
    int s1 = atomicAdd(&lhist[k1], 1);
    sorted[lbase[k1] + s1] = (k1 << 18) | (t0 + 512 + tid);
}

// ---------------------------------------------------------------------------
// Gather-reduce: 1024 blocks x 256 contiguous sorted entries.  lane = dim,
// wave owns 64 contiguous entries; int64 fixed-point accumulate, wave-uniform
// flush per code boundary via global atomicAdd(u64).  Exact + deterministic.
// ---------------------------------------------------------------------------
__global__ __launch_bounds__(256) void gather_kernel(
    const float* __restrict__ x, const int* __restrict__ sorted,
    unsigned long long* __restrict__ gsum)
{
    __shared__ int le[256];
    const int tid = threadIdx.x;
    le[tid] = sorted[blockIdx.x * 256 + tid];
    __syncthreads();
    const int lane = tid & 63, w = tid >> 6;
    const int base = w * 64;

    int e = le[base];
    int kc = e >> 18, t = e & 0x3FFFF;
    float v = x[(size_t)t * DIM + lane];
    int kp = kc;
    long long acc = 0;
#pragma unroll 4
    for (int i = 1; i < 64; ++i) {
        int e1 = le[base + i];
        int k1 = e1 >> 18, t1 = e1 & 0x3FFFF;
        float v1 = x[(size_t)t1 * DIM + lane];   // issued ahead of use
        if (kc != kp) {
            atomicAdd(&gsum[kp * DIM + lane], (unsigned long long)acc);
            acc = 0; kp = kc;
        }
        acc += (long long)rintf(v * FIXS);
        kc = k1; v = v1;
    }
    if (kc != kp) {
        atomicAdd(&gsum[kp * DIM + lane], (unsigned long long)acc);
        acc = 0; kp = kc;
    }
    acc += (long long)rintf(v * FIXS);
    atomicAdd(&gsum[kp * DIM + lane], (unsigned long long)acc);
}

// ---------------------------------------------------------------------------
// Finalize: EMA + division for centroid_sum and vq outputs.
// ---------------------------------------------------------------------------
__global__ __launch_bounds__(512) void finalize_kernel(
    const unsigned long long* __restrict__ gsum,
    const float* __restrict__ cs_old, const float* __restrict__ out_cn,
    float* __restrict__ out_vq, float* __restrict__ out_cs)
{
    int gid = blockIdx.x * 512 + threadIdx.x;
    if (gid >= KCB * DIM) return;
    int k = gid >> 6;
    long long g = (long long)gsum[gid];
    float scs = (float)((double)g * (1.0 / 262144.0));
    float ncs = cs_old[gid] * 0.99f + scs * 0.01f;
    out_cs[gid] = ncs;
    out_vq[gid] = ncs / out_cn[k];
}

// ---------------------------------------------------------------------------
extern "C" void kernel_launch(void* const* d_in, const int* in_sizes, int n_in,
                              void* d_out, int out_size, void* d_ws, size_t ws_size,
                              hipStream_t stream)
{
    const float* x      = (const float*)d_in[0];
    const float* vq     = (const float*)d_in[1];
    const float* cs_old = (const float*)d_in[2];
    const float* cn_old = (const float*)d_in[3];

    float* out_q  = (float*)d_out;
    float* out_vq = out_q + (size_t)N_TOK * DIM;
    float* out_cs = out_vq + (size_t)KCB * DIM;
    float* out_cn = out_cs + (size_t)KCB * DIM;

    char* ws = (char*)d_ws;
    int*    idx       = (int*)(ws);                              // 1 MB
    int*    flag_list = (int*)(ws + (1 << 20));                  // 1 MB (reused as sorted)
    int*    sorted    = flag_list;                               // refine consumes flags first
    int*    flag_cnt  = (int*)(ws + (2 << 20));                  // 4 B
    float*  qhalf     = (float*)(ws + (2 << 20) + 1024);         // 2 KB
    double* qd        = (double*)(ws + (2 << 20) + 4096);        // 4 KB
    int*    counts    = (int*)(ws + (2 << 20) + 8192);           // 2 KB  ← memset start
    int*    cursor    = (int*)(ws + (2 << 20) + 8192 + 2048);    // 2 KB
    unsigned long long* gsum =
        (unsigned long long*)(ws + (2 << 20) + 8192 + 4096);     // 256 KB

    hipMemsetAsync(flag_cnt, 0, 4, stream);
    hipMemsetAsync(counts, 0, 2048 + 2048 + KCB * DIM * 8, stream);

    prep_kernel<<<2, 256, 0, stream>>>(vq, qhalf, qd);
    argmin_mfma_kernel<<<N_TOK / BMT, 512, 0, stream>>>(x, vq, qhalf, idx,
                                                        flag_cnt, flag_list, out_q, counts);
    refine_kernel<<<256, 256, 0, stream>>>(x, vq, qd, flag_cnt, flag_list,
                                           idx, out_q, counts);
    scan_ema_kernel<<<1, 512, 0, stream>>>(counts, cursor, cn_old, out_cn);
    scatter_kernel<<<N_TOK / 1024, 512, 0, stream>>>(idx, cursor, sorted);
    gather_kernel<<<N_TOK / 256, 256, 0, stream>>>(x, sorted, gsum);
    finalize_kernel<<<KCB * DIM / 512, 512, 0, stream>>>(gsum, cs_old, out_cn,
                                                         out_vq, out_cs);
}